// Round 4
// baseline (422.069 us; speedup 1.0000x reference)
//
#include <hip/hip_runtime.h>
#include <math.h>

// Problem constants (unit_gcn): N=64, C=64, T=300, V=25, S=3
//
// ws float layout (fast path A, needs 61,505,536 bytes):
//   [2048, 4096)   : stats, 16 replicas x (sum[64], sumsq[64])
//   [4096, 4224)   : scale[64], shift[64]
//   [4352, 10496)  : W-frag table ushort[12288]: frag f=((s*2+kt)*4+wv), elem lane*8+j
//   [10496, 12032) : A-frag table ushort[3072]:  frag f=(s*2+nt2)
//   byte 65536+    : ypre bf16, natural [n][o][t][w], 30.72M ushort = 61.44 MB
//
// ws float layout (fallback path B, proven R3, needs 40960 bytes):
//   [0,1875) A | [1920,2048) stats | [2048,2176) scsh | [2176..) W-frag | [8320..) A-frag
#define WS_A_BYTES 61505536ull
#define WS_B_BYTES 40960ull

typedef __attribute__((ext_vector_type(8))) short bf16x8;
typedef __attribute__((ext_vector_type(4))) float f32x4;

__device__ inline ushort f2bf(float f) {
    union { float f; unsigned u; } v; v.f = f;
    unsigned r = v.u + 0x7fffu + ((v.u >> 16) & 1u);
    return (ushort)(r >> 16);
}
__device__ inline float bf2f(ushort h) {
    union { unsigned u; float f; } v; v.u = ((unsigned)h) << 16;
    return v.f;
}

// ===========================================================================
// PATH A
// ===========================================================================

// K1a: 8 blocks. All blocks: normalize A into LDS. Block 0: zero stats.
// Frag tables split across blocks (idx = bid*256+tid).
__global__ __launch_bounds__(256) void k_prep_a(const float* __restrict__ PA,
                                                const float* __restrict__ W,
                                                float* __restrict__ ws) {
    __shared__ float Al[1875];
    const int tid = threadIdx.x;
    const int bid = blockIdx.x;
    for (int i = tid; i < 1875; i += 256) Al[i] = PA[i];
    if (bid == 0)
        for (int i = tid; i < 2048; i += 256) ws[2048 + i] = 0.0f;
    __syncthreads();
    if (tid < 75) {
        int s = tid / 25, w = tid - s * 25;
        float ss = 0.0f;
        for (int v = 0; v < 25; ++v) {
            float p = Al[s * 625 + v * 25 + w];
            ss += p * p;
        }
        float inv = 1.0f / (sqrtf(ss) + 1e-4f);
        for (int v = 0; v < 25; ++v) Al[s * 625 + v * 25 + w] *= inv;
    }
    __syncthreads();
    int idx = bid * 256 + tid;
    if (idx < 1536) {  // W-frag: W[s][o=wv*16+col][c=kt*32+quad*8+j]
        ushort* wt = (ushort*)(ws + 4352);
        int lane = idx & 63, rest = idx >> 6;
        int wv = rest & 3, sk = rest >> 2;
        int kt = sk & 1, s = sk >> 1;
        int col = lane & 15, quad = lane >> 4;
        const float* wp = W + s * 4096 + (wv * 16 + col) * 64 + kt * 32 + quad * 8;
#pragma unroll
        for (int j = 0; j < 8; ++j) wt[idx * 8 + j] = f2bf(wp[j]);
    } else if (idx < 1920) {  // A-frag: A[s][v=quad*8+j][w=nt2*16+col], OOB->0
        ushort* at = (ushort*)(ws + 10496);
        int a = idx - 1536;
        int lane = a & 63, rest = a >> 6;
        int nt2 = rest & 1, s = rest >> 1;
        int col = lane & 15, quad = lane >> 4;
        int w = nt2 * 16 + col;
#pragma unroll
        for (int j = 0; j < 8; ++j) {
            int v = quad * 8 + j;
            float av = (v < 25 && w < 25) ? Al[s * 625 + v * 25 + w] : 0.0f;
            at[a * 8 + j] = f2bf(av);
        }
    }
}

// K2a (MFMA): grid (60, 64) = 3840 blocks (5 rounds/CU -> blocks stagger, the
// barrier/atomic stalls of one block overlap other blocks' compute).
//  GEMM1: Z_s[o,(t,v)] = sum_c W_s[o,c] * X[c,(t,v)]   M=64 N=128(pad) K=64
//  GEMM2: y[(t,o),w]  += sum_v Z_s * A_s[v,w]          K=25->32, N=25->2 tiles
// ypre written bf16 (halves y traffic); stats spread over 16 replica lines.
// Bias cancels through training-mode BN -> dropped.
__global__ __launch_bounds__(256) void k_main_a(const float* __restrict__ x,
                                                const float* __restrict__ ws,
                                                ushort* __restrict__ ypre,
                                                float* __restrict__ stats) {
    __shared__ __align__(16) ushort Xl[128 * 72];
    __shared__ __align__(16) ushort Zl[320 * 40];
    __shared__ float sst[128];

    const int tid = threadIdx.x;
    const int wv = tid >> 6;
    const int lane = tid & 63;
    const int col = lane & 15;
    const int quad = lane >> 4;
    const int strip = wv << 4;
    const int n = blockIdx.y;
    const int t0 = blockIdx.x * 5;

    // hoist fragments (L2-hot 27KB tables, 12 x dwordx4 per lane)
    const ushort* wt = (const ushort*)(ws + 4352);
    const ushort* at = (const ushort*)(ws + 10496);
    bf16x8 wf[3][2], af[3][2];
#pragma unroll
    for (int s = 0; s < 3; ++s) {
#pragma unroll
        for (int kt = 0; kt < 2; ++kt)
            wf[s][kt] = *(const bf16x8*)&wt[(((s * 2 + kt) * 4 + wv) * 64 + lane) * 8];
#pragma unroll
        for (int nt2 = 0; nt2 < 2; ++nt2)
            af[s][nt2] = *(const bf16x8*)&at[((s * 2 + nt2) * 64 + lane) * 8];
    }
    // stage X: x[n, c, t0*25 + tv] -> Xl[tv*72 + c]; tv>=125 zero
    {
        const float* xp = x + n * 480000 + t0 * 25;
#pragma unroll 8
        for (int i = tid; i < 8192; i += 256) {
            int c = i >> 7, tv = i & 127;
            float g = (tv < 125) ? xp[c * 7500 + tv] : 0.0f;
            Xl[tv * 72 + c] = f2bf(g);
        }
    }
    // zero Z pad cols v=25..31 (v=24 also touched, rewritten by GEMM1)
    for (int i = tid; i < 320 * 8; i += 256)
        Zl[(i >> 3) * 40 + 24 + (i & 7)] = 0;
    __syncthreads();

    f32x4 yacc[5][2];
#pragma unroll
    for (int t = 0; t < 5; ++t)
#pragma unroll
        for (int j = 0; j < 2; ++j) yacc[t][j] = (f32x4){0.f, 0.f, 0.f, 0.f};

#pragma unroll
    for (int s = 0; s < 3; ++s) {
        // GEMM1: wave's o-strip of Z (own rows only -> no barrier needed)
#pragma unroll
        for (int nt = 0; nt < 8; ++nt) {
            f32x4 z = (f32x4){0.f, 0.f, 0.f, 0.f};
            const int rb = (nt * 16 + col) * 72 + quad * 8;
            bf16x8 x0 = *(const bf16x8*)&Xl[rb];
            bf16x8 x1 = *(const bf16x8*)&Xl[rb + 32];
            z = __builtin_amdgcn_mfma_f32_16x16x32_bf16(wf[s][0], x0, z, 0, 0, 0);
            z = __builtin_amdgcn_mfma_f32_16x16x32_bf16(wf[s][1], x1, z, 0, 0, 0);
            int colg = nt * 16 + col;
            if (colg < 125) {
                int t = (colg * 41) >> 10;  // /25, exact for colg<128
                int v = colg - t * 25;
                int row = (t << 6) + strip + (quad << 2);
#pragma unroll
                for (int r = 0; r < 4; ++r) Zl[(row + r) * 40 + v] = f2bf(z[r]);
            }
        }
        // GEMM2: consume own Z rows (intra-wave LDS dependency only)
#pragma unroll
        for (int t = 0; t < 5; ++t) {
            bf16x8 zf = *(const bf16x8*)&Zl[((t << 6) + strip + col) * 40 + quad * 8];
            yacc[t][0] = __builtin_amdgcn_mfma_f32_16x16x32_bf16(zf, af[s][0], yacc[t][0], 0, 0, 0);
            yacc[t][1] = __builtin_amdgcn_mfma_f32_16x16x32_bf16(zf, af[s][1], yacc[t][1], 0, 0, 0);
        }
    }

    // epilogue: D layout col(lane&15)=w(+16*nt2), row(quad*4+r)=o offset
    float ssum[4] = {0.f, 0.f, 0.f, 0.f}, ssq[4] = {0.f, 0.f, 0.f, 0.f};
    const int obase = strip + (quad << 2);
#pragma unroll
    for (int t = 0; t < 5; ++t) {
#pragma unroll
        for (int nt2 = 0; nt2 < 2; ++nt2) {
            int w = nt2 * 16 + col;
            if (w < 25) {
                ushort* yp = ypre + n * 480000 + obase * 7500 + (t0 + t) * 25 + w;
                f32x4 f = yacc[t][nt2];
#pragma unroll
                for (int r = 0; r < 4; ++r) {
                    float yv = f[r];
                    yp[r * 7500] = f2bf(yv);
                    ssum[r] += yv;
                    ssq[r] = fmaf(yv, yv, ssq[r]);
                }
            }
        }
    }
#pragma unroll
    for (int r = 0; r < 4; ++r) {
        float a = ssum[r], b = ssq[r];
        for (int m = 1; m < 16; m <<= 1) {
            a += __shfl_xor(a, m, 64);
            b += __shfl_xor(b, m, 64);
        }
        if (col == 0) {  // unique (wv,quad,r) -> unique o
            sst[obase + r] = a;
            sst[64 + obase + r] = b;
        }
    }
    __syncthreads();
    const int rep = (blockIdx.x + blockIdx.y) & 15;  // spread atomic contention
    if (tid < 128) atomicAdd(&stats[rep * 128 + tid], sst[tid]);
}

// K3: finalize BN scale/shift (nrep replica lines of 128)
__global__ void k_stats(const float* __restrict__ stats, int nrep,
                        const float* __restrict__ gamma,
                        const float* __restrict__ beta,
                        float* __restrict__ scsh) {
    int o = threadIdx.x;
    if (o >= 64) return;
    float su = 0.f, sq = 0.f;
    for (int r = 0; r < nrep; ++r) {
        su += stats[r * 128 + o];
        sq += stats[r * 128 + 64 + o];
    }
    const float invn = 1.0f / 480000.0f;  // N*T*V
    float mean = su * invn;
    float var = sq * invn - mean * mean;
    float inv = rsqrtf(var + 1e-5f);
    float sc = gamma[o] * inv;
    scsh[o] = sc;
    scsh[64 + o] = beta[o] - mean * sc;
}

// K4a: out = relu(sc[o]*bf2f(ypre) + sh[o] + x). Plane-mapped: block = one
// (n,o) plane (4096 blocks), o = blockIdx&63 -> no division, pure streaming.
__global__ __launch_bounds__(256) void k_bnrelu_a(const float* __restrict__ x,
                                                  const ushort* __restrict__ ypre,
                                                  const float* __restrict__ scsh,
                                                  float* __restrict__ out) {
    const int plane = blockIdx.x;  // n*64 + o
    const int o = plane & 63;
    const float sc = scsh[o], sh = scsh[64 + o];
    const ushort* yp = ypre + plane * 7500;
    const float4* xp = (const float4*)(x + plane * 7500);
    float4* op = (float4*)(out + plane * 7500);
    for (int j = threadIdx.x; j < 1875; j += 256) {
        ushort4 yv = ((const ushort4*)yp)[j];
        float4 xx = xp[j];
        float4 r;
        r.x = fmaxf(fmaf(bf2f(yv.x), sc, sh) + xx.x, 0.0f);
        r.y = fmaxf(fmaf(bf2f(yv.y), sc, sh) + xx.y, 0.0f);
        r.z = fmaxf(fmaf(bf2f(yv.z), sc, sh) + xx.z, 0.0f);
        r.w = fmaxf(fmaf(bf2f(yv.w), sc, sh) + xx.w, 0.0f);
        op[j] = r;
    }
}

// ===========================================================================
// PATH B (proven R3 pipeline; ypre fp32 in d_out; plane-mapped bnrelu)
// ===========================================================================
__global__ __launch_bounds__(256) void k_prep_b(const float* __restrict__ PA,
                                                const float* __restrict__ W,
                                                float* __restrict__ ws) {
    __shared__ float Al[1875];
    const int tid = threadIdx.x;
    for (int i = tid; i < 1875; i += 256) Al[i] = PA[i];
    if (tid < 128) ws[1920 + tid] = 0.0f;
    __syncthreads();
    if (tid < 75) {
        int s = tid / 25, w = tid - s * 25;
        float ss = 0.0f;
        for (int v = 0; v < 25; ++v) {
            float p = Al[s * 625 + v * 25 + w];
            ss += p * p;
        }
        float inv = 1.0f / (sqrtf(ss) + 1e-4f);
        for (int v = 0; v < 25; ++v) Al[s * 625 + v * 25 + w] *= inv;
    }
    __syncthreads();
    ushort* wt = (ushort*)(ws + 2176);
    for (int f = tid; f < 1536; f += 256) {
        int lane = f & 63, rest = f >> 6;
        int wv = rest & 3, sk = rest >> 2;
        int kt = sk & 1, s = sk >> 1;
        int col = lane & 15, quad = lane >> 4;
        const float* wp = W + s * 4096 + (wv * 16 + col) * 64 + kt * 32 + quad * 8;
#pragma unroll
        for (int j = 0; j < 8; ++j) wt[f * 8 + j] = f2bf(wp[j]);
    }
    ushort* at = (ushort*)(ws + 8320);
    for (int f = tid; f < 384; f += 256) {
        int lane = f & 63, rest = f >> 6;
        int nt2 = rest & 1, s = rest >> 1;
        int col = lane & 15, quad = lane >> 4;
        int w = nt2 * 16 + col;
#pragma unroll
        for (int j = 0; j < 8; ++j) {
            int v = quad * 8 + j;
            float a = (v < 25 && w < 25) ? Al[s * 625 + v * 25 + w] : 0.0f;
            at[f * 8 + j] = f2bf(a);
        }
    }
}

__global__ __launch_bounds__(256) void k_main_b(const float* __restrict__ x,
                                                const float* __restrict__ ws,
                                                float* __restrict__ ypre,
                                                float* __restrict__ stats) {
    __shared__ __align__(16) ushort Xl[128 * 72];
    __shared__ __align__(16) ushort Zl[320 * 40];
    __shared__ float sst[128];

    const int tid = threadIdx.x;
    const int wv = tid >> 6;
    const int lane = tid & 63;
    const int col = lane & 15;
    const int quad = lane >> 4;
    const int strip = wv << 4;
    const int n = blockIdx.y;
    const int t0 = blockIdx.x * 5;

    const ushort* wt = (const ushort*)(ws + 2176);
    const ushort* at = (const ushort*)(ws + 8320);
    bf16x8 wf[3][2], af[3][2];
#pragma unroll
    for (int s = 0; s < 3; ++s) {
#pragma unroll
        for (int kt = 0; kt < 2; ++kt)
            wf[s][kt] = *(const bf16x8*)&wt[(((s * 2 + kt) * 4 + wv) * 64 + lane) * 8];
#pragma unroll
        for (int nt2 = 0; nt2 < 2; ++nt2)
            af[s][nt2] = *(const bf16x8*)&at[((s * 2 + nt2) * 64 + lane) * 8];
    }
    {
        const float* xp = x + n * 480000 + t0 * 25;
#pragma unroll 8
        for (int i = tid; i < 8192; i += 256) {
            int c = i >> 7, tv = i & 127;
            float g = (tv < 125) ? xp[c * 7500 + tv] : 0.0f;
            Xl[tv * 72 + c] = f2bf(g);
        }
    }
    for (int i = tid; i < 320 * 8; i += 256)
        Zl[(i >> 3) * 40 + 24 + (i & 7)] = 0;
    __syncthreads();

    f32x4 yacc[5][2];
#pragma unroll
    for (int t = 0; t < 5; ++t)
#pragma unroll
        for (int j = 0; j < 2; ++j) yacc[t][j] = (f32x4){0.f, 0.f, 0.f, 0.f};

#pragma unroll
    for (int s = 0; s < 3; ++s) {
#pragma unroll
        for (int nt = 0; nt < 8; ++nt) {
            f32x4 z = (f32x4){0.f, 0.f, 0.f, 0.f};
            const int rb = (nt * 16 + col) * 72 + quad * 8;
            bf16x8 x0 = *(const bf16x8*)&Xl[rb];
            bf16x8 x1 = *(const bf16x8*)&Xl[rb + 32];
            z = __builtin_amdgcn_mfma_f32_16x16x32_bf16(wf[s][0], x0, z, 0, 0, 0);
            z = __builtin_amdgcn_mfma_f32_16x16x32_bf16(wf[s][1], x1, z, 0, 0, 0);
            int colg = nt * 16 + col;
            if (colg < 125) {
                int t = (colg * 41) >> 10;
                int v = colg - t * 25;
                int row = (t << 6) + strip + (quad << 2);
#pragma unroll
                for (int r = 0; r < 4; ++r) Zl[(row + r) * 40 + v] = f2bf(z[r]);
            }
        }
#pragma unroll
        for (int t = 0; t < 5; ++t) {
            bf16x8 zf = *(const bf16x8*)&Zl[((t << 6) + strip + col) * 40 + quad * 8];
            yacc[t][0] = __builtin_amdgcn_mfma_f32_16x16x32_bf16(zf, af[s][0], yacc[t][0], 0, 0, 0);
            yacc[t][1] = __builtin_amdgcn_mfma_f32_16x16x32_bf16(zf, af[s][1], yacc[t][1], 0, 0, 0);
        }
    }

    float ssum[4] = {0.f, 0.f, 0.f, 0.f}, ssq[4] = {0.f, 0.f, 0.f, 0.f};
    const int obase = strip + (quad << 2);
#pragma unroll
    for (int t = 0; t < 5; ++t) {
#pragma unroll
        for (int nt2 = 0; nt2 < 2; ++nt2) {
            int w = nt2 * 16 + col;
            if (w < 25) {
                float* yp = ypre + n * 480000 + obase * 7500 + (t0 + t) * 25 + w;
                f32x4 f = yacc[t][nt2];
#pragma unroll
                for (int r = 0; r < 4; ++r) {
                    float yv = f[r];
                    yp[r * 7500] = yv;
                    ssum[r] += yv;
                    ssq[r] = fmaf(yv, yv, ssq[r]);
                }
            }
        }
    }
#pragma unroll
    for (int r = 0; r < 4; ++r) {
        float a = ssum[r], b = ssq[r];
        for (int m = 1; m < 16; m <<= 1) {
            a += __shfl_xor(a, m, 64);
            b += __shfl_xor(b, m, 64);
        }
        if (col == 0) {
            sst[obase + r] = a;
            sst[64 + obase + r] = b;
        }
    }
    __syncthreads();
    if (tid < 128) atomicAdd(&stats[tid], sst[tid]);
}

__global__ __launch_bounds__(256) void k_bnrelu_b(const float* __restrict__ x,
                                                  const float* __restrict__ scsh,
                                                  float* out) {
    const int plane = blockIdx.x;
    const int o = plane & 63;
    const float sc = scsh[o], sh = scsh[64 + o];
    float4* op = (float4*)(out + plane * 7500);
    const float4* xp = (const float4*)(x + plane * 7500);
    for (int j = threadIdx.x; j < 1875; j += 256) {
        float4 y = op[j];
        float4 xx = xp[j];
        float4 r;
        r.x = fmaxf(fmaf(y.x, sc, sh) + xx.x, 0.0f);
        r.y = fmaxf(fmaf(y.y, sc, sh) + xx.y, 0.0f);
        r.z = fmaxf(fmaf(y.z, sc, sh) + xx.z, 0.0f);
        r.w = fmaxf(fmaf(y.w, sc, sh) + xx.w, 0.0f);
        op[j] = r;
    }
}

// ===========================================================================
extern "C" void kernel_launch(void* const* d_in, const int* in_sizes, int n_in,
                              void* d_out, int out_size, void* d_ws, size_t ws_size,
                              hipStream_t stream) {
    const float* x = (const float*)d_in[0];
    const float* PA = (const float*)d_in[1];
    const float* W = (const float*)d_in[2];
    // d_in[3] = b : cancels through training-mode BN -> unused
    const float* gamma = (const float*)d_in[4];
    const float* beta = (const float*)d_in[5];
    float* wsf = (float*)d_ws;
    float* out = (float*)d_out;

    if (ws_size >= WS_A_BYTES) {
        ushort* ypre = (ushort*)((char*)d_ws + 65536);
        k_prep_a<<<8, 256, 0, stream>>>(PA, W, wsf);
        dim3 g2(60, 64);
        k_main_a<<<g2, 256, 0, stream>>>(x, wsf, ypre, wsf + 2048);
        k_stats<<<1, 64, 0, stream>>>(wsf + 2048, 16, gamma, beta, wsf + 4096);
        k_bnrelu_a<<<4096, 256, 0, stream>>>(x, ypre, wsf + 4096, out);
    } else {
        k_prep_b<<<1, 256, 0, stream>>>(PA, W, wsf);
        dim3 g2(60, 64);
        k_main_b<<<g2, 256, 0, stream>>>(x, wsf, out, wsf + 1920);
        k_stats<<<1, 64, 0, stream>>>(wsf + 1920, 1, gamma, beta, wsf + 2048);
        k_bnrelu_b<<<4096, 256, 0, stream>>>(x, wsf + 2048, out);
    }
}